// Round 1
// baseline (426.859 us; speedup 1.0000x reference)
//
#include <hip/hip_runtime.h>

// Fold3D (stride == kernel_size) = pure permutation:
// out[b, c, p1*8+e1, p2*8+e2, p3*8+e3] = x[b, p1, p2, p3, c, e1, e2, e3]
// Sizes: B=4, P=8, pe=8, NF=64. float32 in/out. 64M elements each way.
//
// Block = one (b, p1, p2, c). Per-block payload = 8 patches (p3) x 512 floats
// = 4096 floats = 1024 float4. Thread-index decomposition (e1,e2,p3,h) makes
// writes perfectly contiguous (wave writes 1 KB runs) and reads fall in full
// 128 B aligned chunks (8 lanes x 16 B per p3 group). No LDS needed.

__global__ __launch_bounds__(256) void fold3d_kernel(
    const float4* __restrict__ x, float4* __restrict__ out) {
    int bid = blockIdx.x;
    int c  = bid & 63;
    int t  = bid >> 6;
    int p2 = t & 7;  t >>= 3;
    int p1 = t & 7;
    int b  = t >> 3;

    // input float4 base (before p3/e terms):
    //   in_f4 = ((((b*8+p1)*8+p2)*8 + p3)*64 + c) * 128 + (e1*8+e2)*2 + h
    const int inBaseBlk = (((b * 8 + p1) * 8 + p2) * 8) * 8192 + c * 128;
    // output float4 base (before e1/e2/p3/h terms):
    //   out_f4 = (((b*64+c)*64 + p1*8+e1)*64 + p2*8+e2)*16 + p3*2 + h
    const int outBaseBlk = ((b * 64 + c) * 64 + p1 * 8) * 64 * 16 + (p2 * 8) * 16;

    #pragma unroll
    for (int k = 0; k < 4; ++k) {
        int o = threadIdx.x + (k << 8);   // [0, 1024)
        int e1 = o >> 7;                  // 0..7
        int r  = o & 127;
        int e2 = r >> 4;                  // 0..7
        int r2 = r & 15;
        int p3 = r2 >> 1;                 // 0..7
        int h  = r2 & 1;                  // 0..1  (e3 half-row)

        int inIdx  = inBaseBlk + p3 * 8192 + (e1 * 8 + e2) * 2 + h;
        int outIdx = outBaseBlk + (e1 * 64 + e2) * 16 + p3 * 2 + h;

        out[outIdx] = x[inIdx];
    }
}

extern "C" void kernel_launch(void* const* d_in, const int* in_sizes, int n_in,
                              void* d_out, int out_size, void* d_ws, size_t ws_size,
                              hipStream_t stream) {
    const float4* x = (const float4*)d_in[0];
    float4* out = (float4*)d_out;
    // grid = B * P * P * NF = 4*8*8*64 = 16384
    dim3 grid(16384), block(256);
    fold3d_kernel<<<grid, block, 0, stream>>>(x, out);
}

// Round 3
// 414.904 us; speedup vs baseline: 1.0288x; 1.0288x over previous
//
#include <hip/hip_runtime.h>

// Fold3D (stride == kernel_size) = pure permutation:
// out[b, c, p1*8+e1, p2*8+e2, p3*8+e3] = x[b, p1, p2, p3, c, e1, e2, e3]
// B=4, P=8, pe=8, NF=64, float32. 256 MB in + 256 MB out.
//
// Block = one (b, p1, p2, c); 256 threads; 4 float4/thread.
// Wave-slot s = w*4+k handles (e1 = s>>1, e2-half = s&1):
//   READ:  lane l = p3*8 + q. 8 consecutive lanes read one 128 B-aligned
//          contiguous segment -> 8 full-line segments per wave instruction.
//   SHUFFLE: in-wave permute so lane d holds out-offset d:
//          d = e2'*16 + p3*2 + h  =>  src(d) = ((d>>1)&7)*8 + (d>>4)*2 + (d&1)
//   WRITE: wave stores 64 consecutive float4s = 1 KB contiguous run.
// No LDS; 4 ds_bpermute per float4.

typedef float v4f __attribute__((ext_vector_type(4)));

__global__ __launch_bounds__(256) void fold3d_kernel(
    const v4f* __restrict__ x, v4f* __restrict__ out) {
    int bid = blockIdx.x;
    int c  = bid & 63;
    int t  = bid >> 6;
    int p2 = t & 7;  t >>= 3;
    int p1 = t & 7;
    int b  = t >> 3;

    // float4-unit bases
    const int inBase  = (((b * 8 + p1) * 8 + p2) * 8) * 8192 + c * 128;
    const int outBase = ((b * 64 + c) * 64 + p1 * 8) * 1024 + p2 * 128;

    const int lane = threadIdx.x & 63;
    const int w    = threadIdx.x >> 6;

    // shuffle source lane: lane d needs data loaded by lane src
    const int d   = lane;
    const int src = (((d >> 1) & 7) << 3) + ((d >> 4) << 1) + (d & 1);

    // per-lane read offset: p3*8192 + q
    const int inLane = ((lane >> 3) << 13) + (lane & 7);

    v4f v[4];
    #pragma unroll
    for (int k = 0; k < 4; ++k) {
        int s = (w << 2) + k;                       // wave-slot: e1=s>>1, e2h=s&1
        int inIdx = inBase + inLane + ((s >> 1) << 4) + ((s & 1) << 3);
        v[k] = __builtin_nontemporal_load(&x[inIdx]);
    }

    #pragma unroll
    for (int k = 0; k < 4; ++k) {
        int s = (w << 2) + k;
        v4f g;
        g.x = __shfl(v[k].x, src);
        g.y = __shfl(v[k].y, src);
        g.z = __shfl(v[k].z, src);
        g.w = __shfl(v[k].w, src);
        int outIdx = outBase + ((s >> 1) << 10) + ((s & 1) << 6) + d;
        __builtin_nontemporal_store(g, &out[outIdx]);
    }
}

extern "C" void kernel_launch(void* const* d_in, const int* in_sizes, int n_in,
                              void* d_out, int out_size, void* d_ws, size_t ws_size,
                              hipStream_t stream) {
    const v4f* x = (const v4f*)d_in[0];
    v4f* out = (v4f*)d_out;
    dim3 grid(16384), block(256);   // B*P*P*NF = 4*8*8*64
    fold3d_kernel<<<grid, block, 0, stream>>>(x, out);
}

// Round 4
// 414.742 us; speedup vs baseline: 1.0292x; 1.0004x over previous
//
#include <hip/hip_runtime.h>

// Fold3D (stride == kernel_size) = pure permutation:
// out[b, c, p1*8+e1, p2*8+e2, p3*8+e3] = x[b, p1, p2, p3, c, e1, e2, e3]
// B=4, P=8, pe=8, NF=64, float32. 256 MB in + 256 MB out.
//
// Block = one (b, p1, p2, c0..c0+1); 256 threads; 8 float4/thread.
//   READ:  8 consecutive lanes read one 128 B-aligned contiguous segment
//          -> 8 full-line segments per wave-load instruction.
//   SHUFFLE: in-wave permute (4 ds_bpermute per float4) to output order:
//          d = e2'*16 + p3*2 + h  =>  src(d) = ((d>>1)&7)*8 + (d>>4)*2 + (d&1)
//   WRITE: wave stores 64 consecutive float4s = 1 KB contiguous run.
// Two c-channels per block: 8 loads in flight per thread (2x ILP), and the
// block's read footprint per patch row becomes 4 KB contiguous.

typedef float v4f __attribute__((ext_vector_type(4)));

__global__ __launch_bounds__(256) void fold3d_kernel(
    const v4f* __restrict__ x, v4f* __restrict__ out) {
    int bid = blockIdx.x;
    int c0 = (bid & 31) << 1;          // c = c0 + cc, cc in {0,1}
    int t  = bid >> 5;
    int p2 = t & 7;  t >>= 3;
    int p1 = t & 7;
    int b  = t >> 3;

    const int lane = threadIdx.x & 63;
    const int w    = threadIdx.x >> 6;

    // shuffle source lane: lane d needs data loaded by lane src
    const int d   = lane;
    const int src = (((d >> 1) & 7) << 3) + ((d >> 4) << 1) + (d & 1);

    // per-lane read offset: p3*8192 + q
    const int inLane = ((lane >> 3) << 13) + (lane & 7);

    const int inBase0  = (((b * 8 + p1) * 8 + p2) * 8) * 8192 + c0 * 128;
    const int outBase0 = ((b * 64 + c0) * 64 + p1 * 8) * 1024 + p2 * 128;

    v4f v[2][4];
    #pragma unroll
    for (int cc = 0; cc < 2; ++cc) {
        #pragma unroll
        for (int k = 0; k < 4; ++k) {
            int s = (w << 2) + k;              // e1 = s>>1, e2-half = s&1
            int inIdx = inBase0 + cc * 128 + inLane + ((s >> 1) << 4) + ((s & 1) << 3);
            v[cc][k] = __builtin_nontemporal_load(&x[inIdx]);
        }
    }

    #pragma unroll
    for (int cc = 0; cc < 2; ++cc) {
        #pragma unroll
        for (int k = 0; k < 4; ++k) {
            int s = (w << 2) + k;
            v4f g;
            g.x = __shfl(v[cc][k].x, src);
            g.y = __shfl(v[cc][k].y, src);
            g.z = __shfl(v[cc][k].z, src);
            g.w = __shfl(v[cc][k].w, src);
            int outIdx = outBase0 + cc * 65536 + ((s >> 1) << 10) + ((s & 1) << 6) + d;
            __builtin_nontemporal_store(g, &out[outIdx]);
        }
    }
}

extern "C" void kernel_launch(void* const* d_in, const int* in_sizes, int n_in,
                              void* d_out, int out_size, void* d_ws, size_t ws_size,
                              hipStream_t stream) {
    const v4f* x = (const v4f*)d_in[0];
    v4f* out = (v4f*)d_out;
    dim3 grid(8192), block(256);   // B*P*P*(NF/2) = 4*8*8*32
    fold3d_kernel<<<grid, block, 0, stream>>>(x, out);
}